// Round 12
// baseline (333.994 us; speedup 1.0000x reference)
//
#include <hip/hip_runtime.h>
#include <hip/hip_bf16.h>

// Net_22625887715641: fused conv-feats + channel-normalize + 32x32 normalized
// cross-correlation (23x23 shifts, 362x362 templates).
//
// R22 vs R21 (corr 127us, VGPR 84+96=180 > 170 cap, occ 24%):
//  R21 post-mortem: B-dedup mechanism again confirmed (conflicts 7.05M ->
//  3.57M) but arch-VGPR 84 missed the <=74 needed for 3 waves/SIMD. The
//  LDS-reduction epilogue (temps+addressing live over 96 acc AGPRs) was
//  the high-water mark; R19's burden was stateful staging (80 VGPR).
//  R22 removes BOTH:
//  - Direct atomics from both K-half waves (R19-verified numerics; +37MB
//    atomic writes ~6us, cheap vs regaining 3 waves/SIMD).
//  - Keep R21's stateless B staging (no persistent staging regs).
//  - A-row pointers pre-offset by kh*6144 (no per-iter ktg arithmetic).
//  - __attribute__((amdgpu_waves_per_eu(3))) to pin the allocator to the
//    170-reg budget.
//  Target: arch VGPR ~70 -> 166 unified -> 3 waves/SIMD, halved B traffic
//  finally paying. Tripwire: VGPR>74 => dedup line dead, revert to R20.
//  - feat/pack/prep unchanged.

typedef unsigned short ushort_t;
typedef unsigned int uint_t;
typedef unsigned char uchar_t;
typedef __attribute__((ext_vector_type(4))) float f32x4;
typedef __attribute__((ext_vector_type(16))) float f32x16;
typedef __attribute__((ext_vector_type(4))) uint_t uint4_t;
typedef __attribute__((ext_vector_type(2))) uint_t uint2_t;
typedef __attribute__((ext_vector_type(8))) int int8v;

#define EPSF 2.2204460492503131e-16f
#define X1_N (32*384*384)
#define X2_N (32*32*23*23)

// filtb: fp8 [372 rows][kt64 6][h 2][kg 2][o 32][16B]; row = yf+5
#define FILTB_ROW_B 12288
#define FILTB_BYTES (372*48*32*8)
// prevb: fp8 [32 c][385 rows][432 x]; data rows 0..383 cols 0..383; zeros else
#define PREVB_STRIDE 432
#define PREVB_BYTES (32*385*PREVB_STRIDE)
#define ZERO_BYTES ((size_t)FILTB_BYTES + PREVB_BYTES)
// fT2: fp32 [16 chp][45 rows][12] after prevb
#define FT2_ELEMS (16*45*12)

#define YMAX 367            // y-steps 0..366
#define NCHUNKS 16          // 16 chpairs x 16 chunks = 256 blocks = 1/CU
#define INV_AREA (1.0f/131044.0f)

// One prev y-row image in LDS: [dyb 4][copy 8][432]; copy stride 432
#define SB_COPY_B 432
#define SB_DYB_B  (8*SB_COPY_B)     // 3456
#define SB_ROW_B  (4*SB_DYB_B)      // 13824 B per y-row image
#define SB_BYTES  (2*2*SB_ROW_B)    // [group][buf] = 55296 B

// A-ring: 8 slots x one filtb row
#define SA_BYTES  (8*FILTB_ROW_B)   // 98304 B
#define SMEM_TOTAL (SA_BYTES + SB_BYTES)   // 153600 B

// ---------------------------------------------------------------------------
// fp32 -> fp8 e4m3 (OCP), RNE, input assumed in [0, 448).
// ---------------------------------------------------------------------------
__device__ __forceinline__ uint_t f32_to_e4m3(float f) {
  if (f < 0.015625f)                         // subnormal: m * 2^-9
    return (uint_t)__float2int_rn(f * 512.0f);
  uint_t b = __builtin_bit_cast(uint_t, f);
  int e = (int)(b >> 23) - 127;
  uint_t m = b & 0x7FFFFFu;
  uint_t keep = m >> 20;
  uint_t rest = m & 0xFFFFFu;
  keep += (rest > 0x80000u) || (rest == 0x80000u && (keep & 1u));
  if (keep == 8u) { keep = 0u; e += 1; }
  if (e > 8) return 0x7Eu;                   // saturate 448
  return (uint_t)(((e + 7) << 3) | keep);
}

// ---------------------------------------------------------------------------
// Prep: pack filters to [chp][45][12] (rows 16B-aligned, b-contiguous).
// ---------------------------------------------------------------------------
__global__ void prep_kernel(const float* __restrict__ ft, const float* __restrict__ fn,
                            float* __restrict__ fT2)
{
  const int e = blockIdx.x * 256 + threadIdx.x;
  if (e < FT2_ELEMS) {
    const int chp = e / 540;
    const int rem = e - chp * 540;
    const int row = rem / 12;
    const int j = rem - row * 12;
    float v = 0.f;
    if (j < 11) {
      if (row < 33)      v = ft[chp * 363 + row * 11 + j];        // row = t*11+a
      else if (row < 44) v = fn[chp * 121 + (row - 33) * 11 + j]; // row-33 = a
    }
    fT2[e] = v;
  }
}

// ---------------------------------------------------------------------------
// Stage 1: thread = (ch-pair chp) x (16-px row). Block 128 = 8 rows x 16 chp.
// mode 0: x -> x1 (fp32, LDS-transposed coalesced stores).
// mode 1: xprev -> prevb (fp8 e4m3).
// ---------------------------------------------------------------------------
__global__ __launch_bounds__(128, 4) void feat_kernel(
    const float* __restrict__ xcur, const float* __restrict__ xprev,
    const float* __restrict__ fT2,
    float* __restrict__ out_x1, uchar_t* __restrict__ prevb)
{
  __shared__ float sPx[3 * 18 * 28];
  __shared__ float sOut[32][9][20];    // [ch][r pad 9][px pad 20] bank-safe
  const int tid = threadIdx.x;
  const int chp = tid & 15;
  const int r = tid >> 4;              // 0..7
  const int j0 = blockIdx.x * 16;
  const int i0 = blockIdx.y * 8;
  const int i = i0 + r;
  const int mode = blockIdx.z;
  const float* __restrict__ xin = mode ? xprev : xcur;

  for (int e = tid; e < 3 * 18 * 26; e += 128) {
    const int t = e / 468;
    const int rem = e - t * 468;
    const int ri = rem / 26;
    const int ci = rem - ri * 26;
    sPx[(t * 18 + ri) * 28 + ci] = xin[((size_t)t * 394 + i0 + ri) * 394 + j0 + ci];
  }
  __syncthreads();

  const float* __restrict__ fbase = fT2 + chp * 540;

  float accT[16], accN[16];
#pragma unroll
  for (int p = 0; p < 16; ++p) { accT[p] = 0.f; accN[p] = 0.f; }

#pragma unroll
  for (int t = 0; t < 3; ++t) {
    for (int a = 0; a < 11; ++a) {
      const float* row = &sPx[(t * 18 + r + a) * 28];
      float wv[26];
#pragma unroll
      for (int k = 0; k < 6; ++k) {
        const f32x4 q = *(const f32x4*)(row + 4 * k);
        wv[4 * k + 0] = q[0]; wv[4 * k + 1] = q[1];
        wv[4 * k + 2] = q[2]; wv[4 * k + 3] = q[3];
      }
      wv[24] = row[24]; wv[25] = row[25];

      const float* fr = fbase + (t * 11 + a) * 12;
      const f32x4 fq0 = *(const f32x4*)(fr);
      const f32x4 fq1 = *(const f32x4*)(fr + 4);
      const f32x4 fq2 = *(const f32x4*)(fr + 8);
      float fv[12];
#pragma unroll
      for (int k = 0; k < 4; ++k) { fv[k] = fq0[k]; fv[4+k] = fq1[k]; fv[8+k] = fq2[k]; }
      float fv2[12];
      if (t == 2) {
        const float* fr2 = fbase + (33 + a) * 12;
        const f32x4 g0 = *(const f32x4*)(fr2);
        const f32x4 g1 = *(const f32x4*)(fr2 + 4);
        const f32x4 g2 = *(const f32x4*)(fr2 + 8);
#pragma unroll
        for (int k = 0; k < 4; ++k) { fv2[k] = g0[k]; fv2[4+k] = g1[k]; fv2[8+k] = g2[k]; }
      }

#pragma unroll
      for (int b = 0; b < 11; ++b) {
        const float fT = fv[b];
#pragma unroll
        for (int p = 0; p < 16; ++p) accT[p] = fmaf(wv[b + p], fT, accT[p]);
        if (t == 2) {
          const float fN = fv2[b];
#pragma unroll
          for (int p = 0; p < 16; ++p) accN[p] = fmaf(wv[b + p], fN, accN[p]);
        }
      }
    }
  }

  float o0[16], o1[16];
#pragma unroll
  for (int p = 0; p < 16; ++p) {
    const float vT = fmaxf(accT[p], 0.f) * 0.5f;   // temp: relu(conv)/2
    const float vN = fmaxf(accN[p], 0.f);
    float s = vT + vN;
    s += __shfl_xor(s, 1);  s += __shfl_xor(s, 2);
    s += __shfl_xor(s, 4);  s += __shfl_xor(s, 8);
    const float inv = 1.f / (s + EPSF);
    o0[p] = vT * inv;
    o1[p] = vN * inv;
  }

  if (mode == 0) {
    // Stage to LDS, then write 64B-contiguous segments (4 lanes per line).
#pragma unroll
    for (int p = 0; p < 16; ++p) {
      sOut[chp][r][p] = o0[p];
      sOut[chp + 16][r][p] = o1[p];
    }
    __syncthreads();
#pragma unroll
    for (int it = 0; it < 8; ++it) {
      const int idx = it * 128 + tid;        // 0..1023 = 32ch x 8r x 4seg
      const int seg = idx & 3;
      const int rr = (idx >> 2) & 7;
      const int chn = idx >> 5;
      const f32x4 v = {sOut[chn][rr][4 * seg], sOut[chn][rr][4 * seg + 1],
                       sOut[chn][rr][4 * seg + 2], sOut[chn][rr][4 * seg + 3]};
      *(f32x4*)(out_x1 + (size_t)chn * 147456 + (i0 + rr) * 384 + j0 + 4 * seg) = v;
    }
  } else {
    uint4_t u0, u1;
#pragma unroll
    for (int q = 0; q < 4; ++q) {
      u0[q] = f32_to_e4m3(o0[4*q]) | (f32_to_e4m3(o0[4*q+1]) << 8) |
              (f32_to_e4m3(o0[4*q+2]) << 16) | (f32_to_e4m3(o0[4*q+3]) << 24);
      u1[q] = f32_to_e4m3(o1[4*q]) | (f32_to_e4m3(o1[4*q+1]) << 8) |
              (f32_to_e4m3(o1[4*q+2]) << 16) | (f32_to_e4m3(o1[4*q+3]) << 24);
    }
    *(uint4_t*)(prevb + ((size_t)chp * 385 + i) * PREVB_STRIDE + j0) = u0;
    *(uint4_t*)(prevb + ((size_t)(chp + 16) * 385 + i) * PREVB_STRIDE + j0) = u1;
  }
}

// ---------------------------------------------------------------------------
// Pack x1 (fp32, cropped) into filtb fp8 MFMA-A layout; coalesced 8B writes.
// Layout per row: [kt64 6][h 2][kg 2][o 32][16B]; element k = xb*8+j:
// kt64 = xb>>3, kg = (xb>>2)&1, h = (xb>>1)&1, byte16 = (xb&1)*8 + j.
// ---------------------------------------------------------------------------
__global__ __launch_bounds__(256) void pack_kernel(
    const float* __restrict__ x1, uchar_t* __restrict__ filtb)
{
  const int e = blockIdx.x * 256 + threadIdx.x;
  if (e >= 362 * 46 * 32) return;
  const int o = e & 31;
  const int q = e >> 5;
  const int xb = q % 46;
  const int rowr = q / 46 + 5;          // 5..366
  const int i = rowr + 6;               // 11..372
  const int j0 = 11 + xb * 8;
  const float* src = x1 + (size_t)o * 147456 + i * 384 + j0;
  uint_t w0 = 0, w1 = 0;
#pragma unroll
  for (int k = 0; k < 4; ++k) {
    w0 |= f32_to_e4m3((j0 + k     <= 372) ? src[k]     : 0.f) << (8 * k);
    w1 |= f32_to_e4m3((j0 + 4 + k <= 372) ? src[4 + k] : 0.f) << (8 * k);
  }
  uint2_t u = {w0, w1};
  const int off = (xb >> 3) * 2048 + ((xb >> 1) & 1) * 1024 +
                  ((xb >> 2) & 1) * 512 + o * 16 + (xb & 1) * 8;
  *(uint2_t*)(filtb + (size_t)rowr * FILTB_ROW_B + off) = u;
}

// ---------------------------------------------------------------------------
// Stage 2: correlation via MX-scaled 32x32x64 fp8 MFMA (unit scales).
//   out[o,c,dy,dx] = sum_{y,x} filt[o][y-dy_a][x] * prev[c][y+6*dy_b][x+dx]
//   M=192=(dy_a 6)x(o 32); N=96: n = dyb*24+dx (dx 0..22, 23=pad);
//   K=(y, x): 6 kt64 steps per y, SPLIT across 2 K-half waves.
// Block 768 thr = 12 waves = 2 channel groups x (3 dy_a-pairs x 2 K-halves).
// Wave (cg, p, kh): dy_a in {2p, 2p+1}, kt64 in {3kh..3kh+2}, all 3 nt;
// one Bf read feeds TWO MFMAs (B LDS reads halve). SIMD placement 3,3,3,3.
// acc[2][3] = 96 AGPR; stateless B staging (tasks spread via tid%3); only
// A's 4-reg aval spans the K-loop. Epilogue: DIRECT atomics from both
// K-half waves (x2 pre-zeroed; partial sums add associatively) — no LDS
// reduction, keeping arch VGPR <= 74 for 3 waves/SIMD.
// A: 8-slot LDS ring shared by both groups; wave reads slots (y+5-dya)&7.
// B: per-group double-buffered shifted-copy image (copy s = byte-shift s).
// Operand map (32x32x64 f8f6f4): m/n = lane&31, k = (lane>>5)*32 + j.
// C/D map: col = lane&31, row = (reg&3)+8*(reg>>2)+4*(lane>>5).
// ---------------------------------------------------------------------------
__global__ __launch_bounds__(768, 3)
__attribute__((amdgpu_waves_per_eu(3)))
void corr_kernel(
    const uchar_t* __restrict__ filtb, const uchar_t* __restrict__ prevb,
    float* __restrict__ x2)
{
  extern __shared__ uchar_t smem[];          // [A ring 98304][B 55296]

  const int tid = threadIdx.x;
  const int lane = tid & 63;
  const int wv = tid >> 6;               // 0..11
  const int cg = (wv >= 6) ? 1 : 0;      // channel sub-group
  const int gw = wv - 6 * cg;            // 0..5
  const int p = gw >> 1;                 // dy_a pair 0..2
  const int kh = gw & 1;                 // K-half 0..1
  const int kg = lane >> 5;              // k-group 0..1
  const int nn = lane & 31;              // n (or o) within tile

  const int chpair = blockIdx.x / NCHUNKS;     // 0..15
  const int chunk = blockIdx.x % NCHUNKS;      // 0..15; %8 == XCD
  const int ch = 2 * chpair + cg;              // 0..31
  const int y0 = (chunk * YMAX) / NCHUNKS;     // balanced 22-23 y-steps
  const int y1 = ((chunk + 1) * YMAX) / NCHUNKS;

  uint_t* const sBall = (uint_t*)(smem + SA_BYTES);
  uint_t* const sBg = sBall + cg * (2 * (SB_ROW_B / 4));

  // Per-lane B window byte offsets within a y-row image (32B contiguous,
  // 8B-aligned): copy s = dx&7 is the row shifted by s bytes. kh's base kt
  // offset (3 kt x 64B) folded in.
  int boffB[3];
#pragma unroll
  for (int nt = 0; nt < 3; ++nt) {
    const int n = nt * 32 + nn;          // 0..95
    const int dyb = n / 24;
    const int dxr = n - 24 * dyb;
    const int dx = (dxr < 23) ? dxr : 22;      // pad lane reads valid data
    const int s = dx & 7;
    boffB[nt] = dyb * SB_DYB_B + s * SB_COPY_B + (dx >> 3) * 8 + kg * 32
              + kh * 192;
  }

  // B staging: 208 tasks (2 groups x 104) spread across waves via tid%3.
  const int btask = tid / 3;                   // 0..255
  const bool b_act = ((tid % 3) == 0) && (btask < 208);
  const int bgroup = b_act ? (btask / 104) : 0;
  const int t104 = btask - 104 * (b_act ? (btask / 104) : 0);
  const int sdyb = b_act ? (t104 / 26) : 0;
  const int sg = t104 - 26 * (b_act ? (t104 / 26) : 0);
  const uchar_t* srcbase =
      prevb + ((size_t)((2 * chpair + bgroup) * 385 + 6 * sdyb)) * PREVB_STRIDE;
  uint_t* const bdst0 = sBall + bgroup * (2 * (SB_ROW_B / 4)) +
                        sdyb * (SB_DYB_B / 4) + 4 * sg;

  // Stateless B stage: load row yy (24B window), write 8 shifted copies.
  auto stage_B = [&](int yy, int buf) {
    const uint_t* sw = (const uint_t*)(srcbase + (size_t)yy * PREVB_STRIDE) + 4 * sg;
    const uint4_t lo = *(const uint4_t*)(sw);
    const uint2_t hi = *(const uint2_t*)(sw + 4);
    const uint_t wd[6] = {lo.x, lo.y, lo.z, lo.w, hi.x, hi.y};
    uint_t* dst = bdst0 + buf * (SB_ROW_B / 4);
#pragma unroll
    for (int s = 0; s < 8; ++s) {
      const int off = s >> 2;
      const int b = (s & 3) * 8;
      uint4_t v;
      if (b == 0) {
        v = uint4_t{wd[off], wd[off + 1], wd[off + 2], wd[off + 3]};
      } else {
        v = uint4_t{(wd[off]     >> b) | (wd[off + 1] << (32 - b)),
                    (wd[off + 1] >> b) | (wd[off + 2] << (32 - b)),
                    (wd[off + 2] >> b) | (wd[off + 3] << (32 - b)),
                    (wd[off + 3] >> b) | (wd[off + 4] << (32 - b))};
      }
      *(uint4_t*)(dst + s * (SB_COPY_B / 4)) = v;
    }
  };

  f32x16 acc[2][3];
#pragma unroll
  for (int m = 0; m < 2; ++m)
#pragma unroll
    for (int nt = 0; nt < 3; ++nt)
#pragma unroll
      for (int r = 0; r < 16; ++r) acc[m][nt][r] = 0.f;

  // ---- Prologue ----
  // A: stage 6 filt rows y0..y0+5 into ring slots (row&7); 768 thr x 16B.
#pragma unroll 1
  for (int r6 = 0; r6 < 6; ++r6) {
    const uint4_t v = *(const uint4_t*)(
        filtb + (size_t)(y0 + r6) * FILTB_ROW_B + tid * 16);
    *(uint4_t*)(smem + ((y0 + r6) & 7) * FILTB_ROW_B + tid * 16) = v;
  }
  if (b_act) stage_B(y0, 0);
  __syncthreads();                       // A rows y0..y0+5 + B buf0 staged

  for (int y = y0; y < y1; ++y) {
    const int pb = (y - y0) & 1;         // B buffer being read this iteration

    // A: pre-issue global load of filt row y+6 (4 regs across K-loop).
    const bool a_act = (y + 6 <= y1 + 4);
    uint4_t aval;
    if (a_act)
      aval = *(const uint4_t*)(filtb + (size_t)(y + 6) * FILTB_ROW_B + tid * 16);

    const char* sBrd = (const char*)sBg + pb * SB_ROW_B;
    // A rows for this wave's two dy_a values (2p -> row y+5-2p, 2p+1 ->
    // row y+4-2p), pre-offset by the K-half base (kh*3 kt x 2048B).
    const char* aRow0 = (const char*)smem +
        ((y + 5 - 2 * p) & 7) * FILTB_ROW_B + kh * 6144 + kg * 512 + nn * 16;
    const char* aRow1 = (const char*)smem +
        ((y + 4 - 2 * p) & 7) * FILTB_ROW_B + kh * 6144 + kg * 512 + nn * 16;

    // K-loop: 3 kt64 steps (this wave's K-half), pure LDS, minimal regs.
#pragma unroll 1
    for (int kt = 0; kt < 3; ++kt) {
      const uint4_t a00 = *(const uint4_t*)(aRow0 + (kt << 11));
      const uint4_t a01 = *(const uint4_t*)(aRow0 + (kt << 11) + 1024);
      const int8v Af0 = {(int)a00.x, (int)a00.y, (int)a00.z, (int)a00.w,
                         (int)a01.x, (int)a01.y, (int)a01.z, (int)a01.w};
      const uint4_t a10 = *(const uint4_t*)(aRow1 + (kt << 11));
      const uint4_t a11 = *(const uint4_t*)(aRow1 + (kt << 11) + 1024);
      const int8v Af1 = {(int)a10.x, (int)a10.y, (int)a10.z, (int)a10.w,
                         (int)a11.x, (int)a11.y, (int)a11.z, (int)a11.w};
#pragma unroll
      for (int nt = 0; nt < 3; ++nt) {
        const char* bp = sBrd + boffB[nt] + (kt << 6);
        const uint2_t b0 = *(const uint2_t*)(bp);
        const uint2_t b1 = *(const uint2_t*)(bp + 8);
        const uint2_t b2 = *(const uint2_t*)(bp + 16);
        const uint2_t b3 = *(const uint2_t*)(bp + 24);
        const int8v Bf = {(int)b0.x, (int)b0.y, (int)b1.x, (int)b1.y,
                          (int)b2.x, (int)b2.y, (int)b3.x, (int)b3.y};
        acc[0][nt] = __builtin_amdgcn_mfma_scale_f32_32x32x64_f8f6f4(
            Af0, Bf, acc[0][nt], 0, 0, 0, 0x7F7F7F7F, 0, 0x7F7F7F7F);
        acc[1][nt] = __builtin_amdgcn_mfma_scale_f32_32x32x64_f8f6f4(
            Af1, Bf, acc[1][nt], 0, 0, 0, 0x7F7F7F7F, 0, 0x7F7F7F7F);
      }
    }

    // A: write staged row into ring slot (y+6)&7 (disjoint from y..y+5).
    if (a_act)
      *(uint4_t*)(smem + ((y + 6) & 7) * FILTB_ROW_B + tid * 16) = aval;
    // B: stateless stage of row y+1 into buf pb^1 (readers of pb^1
    // finished at the end-of-(y-1) barrier).
    if (b_act && y + 1 < y1) stage_B(y + 1, pb ^ 1);

    __syncthreads();                     // A row y+6 + B buf y+1 visible
  }

  // ---- Epilogue: direct atomics from BOTH K-half waves (partials of a
  // zeroed accumulator add associatively; same pattern as chunk partials).
#pragma unroll
  for (int m = 0; m < 2; ++m) {
    const int dya = 2 * p + m;
#pragma unroll
    for (int nt = 0; nt < 3; ++nt) {
      const int n = nt * 32 + nn;
      const int dyb = n / 24;
      const int dxr = n - 24 * dyb;
      if (dxr < 23) {
        const int dy = dya + 6 * dyb;
        if (dy <= 22) {
#pragma unroll
          for (int r = 0; r < 16; ++r) {
            const int o = (r & 3) + 8 * (r >> 2) + 4 * kg;   // C/D row
            atomicAdd(&x2[((o * 32 + ch) * 23 + dy) * 23 + dxr],
                      acc[m][nt][r] * INV_AREA);
          }
        }
      }
    }
  }
}

// ---------------------------------------------------------------------------
extern "C" void kernel_launch(void* const* d_in, const int* in_sizes, int n_in,
                              void* d_out, int out_size, void* d_ws, size_t ws_size,
                              hipStream_t stream)
{
  const float* x     = (const float*)d_in[0];   // [3][394][394]
  const float* xprev = (const float*)d_in[1];
  const float* ft    = (const float*)d_in[2];   // [16][3][11][11]
  const float* fn    = (const float*)d_in[3];   // [16][1][11][11]
  float* out = (float*)d_out;

  uchar_t* filtb = (uchar_t*)d_ws;
  uchar_t* prevb = filtb + FILTB_BYTES;
  float* fT2 = (float*)(prevb + PREVB_BYTES);

  static bool attr_set = false;
  if (!attr_set) {
    (void)hipFuncSetAttribute((const void*)corr_kernel,
        hipFuncAttributeMaxDynamicSharedMemorySize, SMEM_TOTAL);
    attr_set = true;
  }

  // Zero packed buffers (zero padding) and the x2 accumulator.
  hipMemsetAsync(d_ws, 0, ZERO_BYTES, stream);
  hipMemsetAsync(out + X1_N, 0, (size_t)X2_N * sizeof(float), stream);

  prep_kernel<<<dim3((FT2_ELEMS + 255) / 256), 256, 0, stream>>>(ft, fn, fT2);
  feat_kernel<<<dim3(24, 48, 2), 128, 0, stream>>>(x, xprev, fT2, out, prevb);
  pack_kernel<<<dim3((362 * 46 * 32 + 255) / 256), 256, 0, stream>>>(out, filtb);
  corr_kernel<<<dim3(16 * NCHUNKS), 768, SMEM_TOTAL, stream>>>(
      filtb, prevb, out + X1_N);
}

// Round 13
// 276.127 us; speedup vs baseline: 1.2096x; 1.2096x over previous
//
#include <hip/hip_runtime.h>
#include <hip/hip_bf16.h>

// Net_22625887715641: fused conv-feats + channel-normalize + 32x32 normalized
// cross-correlation (23x23 shifts, 362x362 templates).
//
// R23 vs R22 (corr 179us REGRESSION, VGPR 76 > 74 target) / R20 (best:
// total 276.3, corr 124.3):
//  R22 post-mortem: the B-dedup (kh-split) line is DEAD — 3 attempts
//  (R19/R21/R22) all missed the <=74 arch-VGPR gate needed for 3 waves/
//  SIMD with acc=96 AGPR, and the halved per-barrier K-work doubled the
//  relative barrier overhead. Abandon it.
//  R23 = R20 restored verbatim + ONE matched lever:
//  - s_setprio(1) around the consumer K-loop (setprio(0) after). Catalog:
//    setprio is null on lockstep blocks (m190) but +4-39% when waves have
//    ROLE DIVERSITY — R20's producer-consumer split created exactly that
//    regime and never exploited it. Consumers (LDS+MFMA critical path)
//    get issue preference; producers have the whole y-window of slack and
//    fill consumer lgkmcnt-stall slots. Worst case neutral.
//  - feat/pack/prep unchanged.

typedef unsigned short ushort_t;
typedef unsigned int uint_t;
typedef unsigned char uchar_t;
typedef __attribute__((ext_vector_type(4))) float f32x4;
typedef __attribute__((ext_vector_type(16))) float f32x16;
typedef __attribute__((ext_vector_type(4))) uint_t uint4_t;
typedef __attribute__((ext_vector_type(2))) uint_t uint2_t;
typedef __attribute__((ext_vector_type(8))) int int8v;

#define EPSF 2.2204460492503131e-16f
#define X1_N (32*384*384)
#define X2_N (32*32*23*23)

// filtb: fp8 [372 rows][kt64 6][h 2][kg 2][o 32][16B]; row = yf+5
#define FILTB_ROW_B 12288
#define FILTB_BYTES (372*48*32*8)
// prevb: fp8 [32 c][385 rows][432 x]; data rows 0..383 cols 0..383; zeros else
#define PREVB_STRIDE 432
#define PREVB_BYTES (32*385*PREVB_STRIDE)
#define ZERO_BYTES ((size_t)FILTB_BYTES + PREVB_BYTES)
// fT2: fp32 [16 chp][45 rows][12] after prevb
#define FT2_ELEMS (16*45*12)

#define YMAX 367            // y-steps 0..366
#define NCHUNKS 16          // 16 chpairs x 16 chunks = 256 blocks = 1/CU
#define INV_AREA (1.0f/131044.0f)

// One prev y-row image in LDS: [dyb 4][copy 8][432]; copy stride 432
#define SB_COPY_B 432
#define SB_DYB_B  (8*SB_COPY_B)     // 3456
#define SB_ROW_B  (4*SB_DYB_B)      // 13824 B per y-row image
#define SB_BYTES  (2*2*SB_ROW_B)    // [group][buf] = 55296 B

// A-ring: 8 slots x one filtb row
#define SA_BYTES  (8*FILTB_ROW_B)   // 98304 B
#define SMEM_TOTAL (SA_BYTES + SB_BYTES)   // 153600 B

// ---------------------------------------------------------------------------
// fp32 -> fp8 e4m3 (OCP), RNE, input assumed in [0, 448).
// ---------------------------------------------------------------------------
__device__ __forceinline__ uint_t f32_to_e4m3(float f) {
  if (f < 0.015625f)                         // subnormal: m * 2^-9
    return (uint_t)__float2int_rn(f * 512.0f);
  uint_t b = __builtin_bit_cast(uint_t, f);
  int e = (int)(b >> 23) - 127;
  uint_t m = b & 0x7FFFFFu;
  uint_t keep = m >> 20;
  uint_t rest = m & 0xFFFFFu;
  keep += (rest > 0x80000u) || (rest == 0x80000u && (keep & 1u));
  if (keep == 8u) { keep = 0u; e += 1; }
  if (e > 8) return 0x7Eu;                   // saturate 448
  return (uint_t)(((e + 7) << 3) | keep);
}

// ---------------------------------------------------------------------------
// Prep: pack filters to [chp][45][12] (rows 16B-aligned, b-contiguous).
// ---------------------------------------------------------------------------
__global__ void prep_kernel(const float* __restrict__ ft, const float* __restrict__ fn,
                            float* __restrict__ fT2)
{
  const int e = blockIdx.x * 256 + threadIdx.x;
  if (e < FT2_ELEMS) {
    const int chp = e / 540;
    const int rem = e - chp * 540;
    const int row = rem / 12;
    const int j = rem - row * 12;
    float v = 0.f;
    if (j < 11) {
      if (row < 33)      v = ft[chp * 363 + row * 11 + j];        // row = t*11+a
      else if (row < 44) v = fn[chp * 121 + (row - 33) * 11 + j]; // row-33 = a
    }
    fT2[e] = v;
  }
}

// ---------------------------------------------------------------------------
// Stage 1: thread = (ch-pair chp) x (16-px row). Block 128 = 8 rows x 16 chp.
// mode 0: x -> x1 (fp32, LDS-transposed coalesced stores).
// mode 1: xprev -> prevb (fp8 e4m3).
// ---------------------------------------------------------------------------
__global__ __launch_bounds__(128, 4) void feat_kernel(
    const float* __restrict__ xcur, const float* __restrict__ xprev,
    const float* __restrict__ fT2,
    float* __restrict__ out_x1, uchar_t* __restrict__ prevb)
{
  __shared__ float sPx[3 * 18 * 28];
  __shared__ float sOut[32][9][20];    // [ch][r pad 9][px pad 20] bank-safe
  const int tid = threadIdx.x;
  const int chp = tid & 15;
  const int r = tid >> 4;              // 0..7
  const int j0 = blockIdx.x * 16;
  const int i0 = blockIdx.y * 8;
  const int i = i0 + r;
  const int mode = blockIdx.z;
  const float* __restrict__ xin = mode ? xprev : xcur;

  for (int e = tid; e < 3 * 18 * 26; e += 128) {
    const int t = e / 468;
    const int rem = e - t * 468;
    const int ri = rem / 26;
    const int ci = rem - ri * 26;
    sPx[(t * 18 + ri) * 28 + ci] = xin[((size_t)t * 394 + i0 + ri) * 394 + j0 + ci];
  }
  __syncthreads();

  const float* __restrict__ fbase = fT2 + chp * 540;

  float accT[16], accN[16];
#pragma unroll
  for (int p = 0; p < 16; ++p) { accT[p] = 0.f; accN[p] = 0.f; }

#pragma unroll
  for (int t = 0; t < 3; ++t) {
    for (int a = 0; a < 11; ++a) {
      const float* row = &sPx[(t * 18 + r + a) * 28];
      float wv[26];
#pragma unroll
      for (int k = 0; k < 6; ++k) {
        const f32x4 q = *(const f32x4*)(row + 4 * k);
        wv[4 * k + 0] = q[0]; wv[4 * k + 1] = q[1];
        wv[4 * k + 2] = q[2]; wv[4 * k + 3] = q[3];
      }
      wv[24] = row[24]; wv[25] = row[25];

      const float* fr = fbase + (t * 11 + a) * 12;
      const f32x4 fq0 = *(const f32x4*)(fr);
      const f32x4 fq1 = *(const f32x4*)(fr + 4);
      const f32x4 fq2 = *(const f32x4*)(fr + 8);
      float fv[12];
#pragma unroll
      for (int k = 0; k < 4; ++k) { fv[k] = fq0[k]; fv[4+k] = fq1[k]; fv[8+k] = fq2[k]; }
      float fv2[12];
      if (t == 2) {
        const float* fr2 = fbase + (33 + a) * 12;
        const f32x4 g0 = *(const f32x4*)(fr2);
        const f32x4 g1 = *(const f32x4*)(fr2 + 4);
        const f32x4 g2 = *(const f32x4*)(fr2 + 8);
#pragma unroll
        for (int k = 0; k < 4; ++k) { fv2[k] = g0[k]; fv2[4+k] = g1[k]; fv2[8+k] = g2[k]; }
      }

#pragma unroll
      for (int b = 0; b < 11; ++b) {
        const float fT = fv[b];
#pragma unroll
        for (int p = 0; p < 16; ++p) accT[p] = fmaf(wv[b + p], fT, accT[p]);
        if (t == 2) {
          const float fN = fv2[b];
#pragma unroll
          for (int p = 0; p < 16; ++p) accN[p] = fmaf(wv[b + p], fN, accN[p]);
        }
      }
    }
  }

  float o0[16], o1[16];
#pragma unroll
  for (int p = 0; p < 16; ++p) {
    const float vT = fmaxf(accT[p], 0.f) * 0.5f;   // temp: relu(conv)/2
    const float vN = fmaxf(accN[p], 0.f);
    float s = vT + vN;
    s += __shfl_xor(s, 1);  s += __shfl_xor(s, 2);
    s += __shfl_xor(s, 4);  s += __shfl_xor(s, 8);
    const float inv = 1.f / (s + EPSF);
    o0[p] = vT * inv;
    o1[p] = vN * inv;
  }

  if (mode == 0) {
    // Stage to LDS, then write 64B-contiguous segments (4 lanes per line).
#pragma unroll
    for (int p = 0; p < 16; ++p) {
      sOut[chp][r][p] = o0[p];
      sOut[chp + 16][r][p] = o1[p];
    }
    __syncthreads();
#pragma unroll
    for (int it = 0; it < 8; ++it) {
      const int idx = it * 128 + tid;        // 0..1023 = 32ch x 8r x 4seg
      const int seg = idx & 3;
      const int rr = (idx >> 2) & 7;
      const int chn = idx >> 5;
      const f32x4 v = {sOut[chn][rr][4 * seg], sOut[chn][rr][4 * seg + 1],
                       sOut[chn][rr][4 * seg + 2], sOut[chn][rr][4 * seg + 3]};
      *(f32x4*)(out_x1 + (size_t)chn * 147456 + (i0 + rr) * 384 + j0 + 4 * seg) = v;
    }
  } else {
    uint4_t u0, u1;
#pragma unroll
    for (int q = 0; q < 4; ++q) {
      u0[q] = f32_to_e4m3(o0[4*q]) | (f32_to_e4m3(o0[4*q+1]) << 8) |
              (f32_to_e4m3(o0[4*q+2]) << 16) | (f32_to_e4m3(o0[4*q+3]) << 24);
      u1[q] = f32_to_e4m3(o1[4*q]) | (f32_to_e4m3(o1[4*q+1]) << 8) |
              (f32_to_e4m3(o1[4*q+2]) << 16) | (f32_to_e4m3(o1[4*q+3]) << 24);
    }
    *(uint4_t*)(prevb + ((size_t)chp * 385 + i) * PREVB_STRIDE + j0) = u0;
    *(uint4_t*)(prevb + ((size_t)(chp + 16) * 385 + i) * PREVB_STRIDE + j0) = u1;
  }
}

// ---------------------------------------------------------------------------
// Pack x1 (fp32, cropped) into filtb fp8 MFMA-A layout; coalesced 8B writes.
// Layout per row: [kt64 6][h 2][kg 2][o 32][16B]; element k = xb*8+j:
// kt64 = xb>>3, kg = (xb>>2)&1, h = (xb>>1)&1, byte16 = (xb&1)*8 + j.
// ---------------------------------------------------------------------------
__global__ __launch_bounds__(256) void pack_kernel(
    const float* __restrict__ x1, uchar_t* __restrict__ filtb)
{
  const int e = blockIdx.x * 256 + threadIdx.x;
  if (e >= 362 * 46 * 32) return;
  const int o = e & 31;
  const int q = e >> 5;
  const int xb = q % 46;
  const int rowr = q / 46 + 5;          // 5..366
  const int i = rowr + 6;               // 11..372
  const int j0 = 11 + xb * 8;
  const float* src = x1 + (size_t)o * 147456 + i * 384 + j0;
  uint_t w0 = 0, w1 = 0;
#pragma unroll
  for (int k = 0; k < 4; ++k) {
    w0 |= f32_to_e4m3((j0 + k     <= 372) ? src[k]     : 0.f) << (8 * k);
    w1 |= f32_to_e4m3((j0 + 4 + k <= 372) ? src[4 + k] : 0.f) << (8 * k);
  }
  uint2_t u = {w0, w1};
  const int off = (xb >> 3) * 2048 + ((xb >> 1) & 1) * 1024 +
                  ((xb >> 2) & 1) * 512 + o * 16 + (xb & 1) * 8;
  *(uint2_t*)(filtb + (size_t)rowr * FILTB_ROW_B + off) = u;
}

// ---------------------------------------------------------------------------
// Stage 2: correlation via MX-scaled 32x32x64 fp8 MFMA (unit scales).
//   out[o,c,dy,dx] = sum_{y,x} filt[o][y-dy_a][x] * prev[c][y+6*dy_b][x+dx]
//   M=192=(dy_a 6)x(o 32); N=96: n = dyb*24+dx (dx 0..22, 23=pad);
//   K=(y, x): 6 kt64 steps of 64 per y.
// Block 1024 thr = 16 waves, producer-consumer:
//   wv 0-11 = compute: 2 channel groups x 6 dy_a waves (pure-LDS K-loop,
//     0-deep loads, unroll 1). Round-robin placement -> 3 comp/SIMD.
//     s_setprio(1) around the K-loop: consumers are the critical path;
//     producers fill their lgkmcnt-stall slots (role-split regime).
//   wv 12-15 = producers, one per SIMD: ALL staging. wv12,13 -> group 0,
//     wv14,15 -> group 1 for B (104 tasks per group); all 4 waves (ptid
//     0..255, 48B each) for the shared A row.
// A: 8-slot LDS ring shared by both groups; rows y..y+5 live; producers
// write slot (y+6)&7 (disjoint). B: per-group double-buffered shifted-copy
// image; producers write buf pb^1 while consumers read pb. One barrier/y.
// Operand map (32x32x64 f8f6f4): m/n = lane&31, k = (lane>>5)*32 + j.
// C/D map: col = lane&31, row = (reg&3)+8*(reg>>2)+4*(lane>>5).
// ---------------------------------------------------------------------------
__global__ __launch_bounds__(1024, 4) void corr_kernel(
    const uchar_t* __restrict__ filtb, const uchar_t* __restrict__ prevb,
    float* __restrict__ x2)
{
  extern __shared__ uchar_t smem[];          // [A ring 98304][B 55296]

  const int tid = threadIdx.x;
  const int lane = tid & 63;
  const int wv = tid >> 6;               // 0..15
  const bool is_comp = (wv < 12);
  const int pw = wv - 12;                // producers 0..3 (neg for compute)
  const int cgu = is_comp ? ((wv >= 6) ? 1 : 0) : (pw >> 1);  // channel group
  const int w = is_comp ? (wv - 6 * ((wv >= 6) ? 1 : 0)) : 0; // dy_a
  const int kg = lane >> 5;              // k-group 0..1
  const int nn = lane & 31;              // n (or o) within tile

  const int chpair = blockIdx.x / NCHUNKS;     // 0..15
  const int chunk = blockIdx.x % NCHUNKS;      // 0..15; %8 == XCD
  const int ch = 2 * chpair + cgu;             // 0..31
  const int y0 = (chunk * YMAX) / NCHUNKS;     // balanced 22-23 y-steps
  const int y1 = ((chunk + 1) * YMAX) / NCHUNKS;

  uint_t* const sBg = (uint_t*)(smem + SA_BYTES) + cgu * (2 * (SB_ROW_B / 4));

  // Per-lane B window byte offsets within a y-row image (32B contiguous,
  // 8B-aligned): copy s = dx&7 is the row shifted by s bytes.
  int boffB[3];
#pragma unroll
  for (int nt = 0; nt < 3; ++nt) {
    const int n = nt * 32 + nn;          // 0..95
    const int dyb = n / 24;
    const int dxr = n - 24 * dyb;
    const int dx = (dxr < 23) ? dxr : 22;      // pad lane reads valid data
    const int s = dx & 7;
    boffB[nt] = dyb * SB_DYB_B + s * SB_COPY_B + (dx >> 3) * 8 + kg * 32;
  }

  // Producer B staging: 104 tasks per group from 2 waves (128 threads).
  const int tl = is_comp ? 0 : ((pw & 1) * 64 + lane);   // 0..127
  const bool b_act = (!is_comp) && (tl < 104);
  const int sdyb = b_act ? (tl / 26) : 0;
  const int sg = tl - 26 * (b_act ? (tl / 26) : 0);
  const uchar_t* srcbase = prevb + ((size_t)(ch * 385 + 6 * sdyb)) * PREVB_STRIDE;
  const int dstoff = sdyb * (SB_DYB_B / 4) + 4 * sg;     // word offset in buf

  // B: load row yy (24B window), expand to 8 byte-shifted copies in buf.
  auto stage_B = [&](int yy, int buf) {
    const uint_t* sw = (const uint_t*)(srcbase + (size_t)yy * PREVB_STRIDE) + 4 * sg;
    const uint4_t lo = *(const uint4_t*)(sw);
    const uint2_t hi = *(const uint2_t*)(sw + 4);
    const uint_t wd[6] = {lo.x, lo.y, lo.z, lo.w, hi.x, hi.y};
    uint_t* dst = sBg + buf * (SB_ROW_B / 4) + dstoff;
#pragma unroll
    for (int s = 0; s < 8; ++s) {
      const int off = s >> 2;
      const int b = (s & 3) * 8;
      uint4_t v;
      if (b == 0) {
        v = uint4_t{wd[off], wd[off + 1], wd[off + 2], wd[off + 3]};
      } else {
        v = uint4_t{(wd[off]     >> b) | (wd[off + 1] << (32 - b)),
                    (wd[off + 1] >> b) | (wd[off + 2] << (32 - b)),
                    (wd[off + 2] >> b) | (wd[off + 3] << (32 - b)),
                    (wd[off + 3] >> b) | (wd[off + 4] << (32 - b))};
      }
      *(uint4_t*)(dst + s * (SB_COPY_B / 4)) = v;
    }
  };

  // A: producers (ptid 0..255) copy one filtb row (48B each) into a slot.
  const int ptid = is_comp ? 0 : (pw * 64 + lane);
  auto stage_A = [&](int row, int slot) {
    const uchar_t* src = filtb + (size_t)row * FILTB_ROW_B + ptid * 48;
    uchar_t* dst = smem + (size_t)slot * FILTB_ROW_B + ptid * 48;
    const uint4_t v0 = *(const uint4_t*)(src);
    const uint4_t v1 = *(const uint4_t*)(src + 16);
    const uint4_t v2 = *(const uint4_t*)(src + 32);
    *(uint4_t*)(dst) = v0;
    *(uint4_t*)(dst + 16) = v1;
    *(uint4_t*)(dst + 32) = v2;
  };

  f32x16 acc[3];
#pragma unroll
  for (int nt = 0; nt < 3; ++nt)
#pragma unroll
    for (int r = 0; r < 16; ++r) acc[nt][r] = 0.f;

  // ---- Prologue (producers only) ----
  if (!is_comp) {
#pragma unroll
    for (int r6 = 0; r6 < 6; ++r6)
      stage_A(y0 + r6, (y0 + r6) & 7);
    if (b_act) stage_B(y0, 0);
  }
  __syncthreads();                       // A rows y0..y0+5 + B buf0 staged

  for (int y = y0; y < y1; ++y) {
    const int pb = (y - y0) & 1;         // B buffer consumers read this iter

    if (is_comp) {
      const char* sBrd = (const char*)sBg + pb * SB_ROW_B;
      const char* aRow = (const char*)smem +
          ((y + 5 - w) & 7) * FILTB_ROW_B + kg * 512 + nn * 16;

      // K-loop: 6 kt64 steps, pure LDS, minimal live registers.
      // setprio(1): consumer waves are the critical path (role-split
      // regime — producers fill the stall slots).
      __builtin_amdgcn_s_setprio(1);
#pragma unroll 1
      for (int kt = 0; kt < 6; ++kt) {
        const char* ap = aRow + (kt << 11);
        const uint4_t a0 = *(const uint4_t*)(ap);          // h=0
        const uint4_t a1 = *(const uint4_t*)(ap + 1024);   // h=1
        const int8v Af = {(int)a0.x, (int)a0.y, (int)a0.z, (int)a0.w,
                          (int)a1.x, (int)a1.y, (int)a1.z, (int)a1.w};
#pragma unroll
        for (int nt = 0; nt < 3; ++nt) {
          const char* bp = sBrd + boffB[nt] + (kt << 6);
          const uint2_t b0 = *(const uint2_t*)(bp);
          const uint2_t b1 = *(const uint2_t*)(bp + 8);
          const uint2_t b2 = *(const uint2_t*)(bp + 16);
          const uint2_t b3 = *(const uint2_t*)(bp + 24);
          const int8v Bf = {(int)b0.x, (int)b0.y, (int)b1.x, (int)b1.y,
                            (int)b2.x, (int)b2.y, (int)b3.x, (int)b3.y};
          acc[nt] = __builtin_amdgcn_mfma_scale_f32_32x32x64_f8f6f4(
              Af, Bf, acc[nt], 0, 0,                // fmtA=FP8, fmtB=FP8
              0, 0x7F7F7F7F, 0, 0x7F7F7F7F);        // unit E8M0 scales
        }
      }
      __builtin_amdgcn_s_setprio(0);
    } else {
      // Producers: stage B row y+1 into buf pb^1 (consumers read pb), and
      // A row y+6 into ring slot (y+6)&7 (consumers read slots y..y+5).
      if (b_act && y + 1 < y1) stage_B(y + 1, pb ^ 1);
      if (y + 6 <= y1 + 4) stage_A(y + 6, (y + 6) & 7);
    }

    __syncthreads();                     // A row y+6 + B buf y+1 visible
  }

  // Epilogue: scale partials, atomically accumulate into x2[o][c][dy][dx].
  if (is_comp) {
#pragma unroll
    for (int nt = 0; nt < 3; ++nt) {
      const int n = nt * 32 + nn;
      const int dyb = n / 24;
      const int dxr = n - 24 * dyb;
      if (dxr < 23) {
        const int dy = w + 6 * dyb;
        if (dy <= 22) {
#pragma unroll
          for (int r = 0; r < 16; ++r) {
            const int o = (r & 3) + 8 * (r >> 2) + 4 * kg;   // C/D row
            atomicAdd(&x2[((o * 32 + ch) * 23 + dy) * 23 + dxr],
                      acc[nt][r] * INV_AREA);
          }
        }
      }
    }
  }
}

// ---------------------------------------------------------------------------
extern "C" void kernel_launch(void* const* d_in, const int* in_sizes, int n_in,
                              void* d_out, int out_size, void* d_ws, size_t ws_size,
                              hipStream_t stream)
{
  const float* x     = (const float*)d_in[0];   // [3][394][394]
  const float* xprev = (const float*)d_in[1];
  const float* ft    = (const float*)d_in[2];   // [16][3][11][11]
  const float* fn    = (const float*)d_in[3];   // [16][1][11][11]
  float* out = (float*)d_out;

  uchar_t* filtb = (uchar_t*)d_ws;
  uchar_t* prevb = filtb + FILTB_BYTES;
  float* fT2 = (float*)(prevb + PREVB_BYTES);

  static bool attr_set = false;
  if (!attr_set) {
    (void)hipFuncSetAttribute((const void*)corr_kernel,
        hipFuncAttributeMaxDynamicSharedMemorySize, SMEM_TOTAL);
    attr_set = true;
  }

  // Zero packed buffers (zero padding) and the x2 accumulator.
  hipMemsetAsync(d_ws, 0, ZERO_BYTES, stream);
  hipMemsetAsync(out + X1_N, 0, (size_t)X2_N * sizeof(float), stream);

  prep_kernel<<<dim3((FT2_ELEMS + 255) / 256), 256, 0, stream>>>(ft, fn, fT2);
  feat_kernel<<<dim3(24, 48, 2), 128, 0, stream>>>(x, xprev, fT2, out, prevb);
  pack_kernel<<<dim3((362 * 46 * 32 + 255) / 256), 256, 0, stream>>>(out, filtb);
  corr_kernel<<<dim3(16 * NCHUNKS), 1024, SMEM_TOTAL, stream>>>(
      filtb, prevb, out + X1_N);
}

// Round 14
// 261.057 us; speedup vs baseline: 1.2794x; 1.0577x over previous
//
#include <hip/hip_runtime.h>
#include <hip/hip_bf16.h>

// Net_22625887715641: fused conv-feats + channel-normalize + 32x32 normalized
// cross-correlation (23x23 shifts, 362x362 templates).
//
// R24 vs R23 (total 276.1, corr 126.4 — corr plateau confirmed):
//  corr ledger closed: R17/R18/R20/R23 (four schedules) all 124-128us;
//  additive LDS-pipe wall (~75% LDS busy, 27% MFMA); dedup line dead on
//  the register gate (R19/R21/R22). corr is UNTOUCHED this round.
//  Target = the ~150us non-corr tail (6 serial dispatches):
//  - pack_kernel DELETED: feat mode-0 writes filtb fp8 bytes directly
//    (per-pixel guarded byte stores; fp8 is byte-addressable so the
//    16-px-block vs 8-px-group misalignment is a non-issue; byte offset
//    replicates pack's formula exactly; memset provides zero padding).
//    Removes pack's 17MB re-read + one dispatch.
//  - Both hipMemsetAsync folded into prep (extra grid ranges zero
//    filtb+prevb and x2; disjoint regions, stream order preserved).
//  Dispatches 6 -> 3. Prediction: corr unchanged; total ~252-262.

typedef unsigned short ushort_t;
typedef unsigned int uint_t;
typedef unsigned char uchar_t;
typedef __attribute__((ext_vector_type(4))) float f32x4;
typedef __attribute__((ext_vector_type(16))) float f32x16;
typedef __attribute__((ext_vector_type(4))) uint_t uint4_t;
typedef __attribute__((ext_vector_type(2))) uint_t uint2_t;
typedef __attribute__((ext_vector_type(8))) int int8v;

#define EPSF 2.2204460492503131e-16f
#define X1_N (32*384*384)
#define X2_N (32*32*23*23)

// filtb: fp8 [372 rows][kt64 6][h 2][kg 2][o 32][16B]; row = yf+5
#define FILTB_ROW_B 12288
#define FILTB_BYTES (372*48*32*8)
// prevb: fp8 [32 c][385 rows][432 x]; data rows 0..383 cols 0..383; zeros else
#define PREVB_STRIDE 432
#define PREVB_BYTES (32*385*PREVB_STRIDE)
#define ZERO_BYTES ((size_t)FILTB_BYTES + PREVB_BYTES)
// fT2: fp32 [16 chp][45 rows][12] after prevb
#define FT2_ELEMS (16*45*12)

// prep fused-zero ranges (16B units)
#define ZERO16 (ZERO_BYTES / 16)            // 618,336
#define X2Z16  ((X2_N * 4) / 16)            // 135,424
#define PREP_WORK (ZERO16 + X2Z16 + FT2_ELEMS)

#define YMAX 367            // y-steps 0..366
#define NCHUNKS 16          // 16 chpairs x 16 chunks = 256 blocks = 1/CU
#define INV_AREA (1.0f/131044.0f)

// One prev y-row image in LDS: [dyb 4][copy 8][432]; copy stride 432
#define SB_COPY_B 432
#define SB_DYB_B  (8*SB_COPY_B)     // 3456
#define SB_ROW_B  (4*SB_DYB_B)      // 13824 B per y-row image
#define SB_BYTES  (2*2*SB_ROW_B)    // [group][buf] = 55296 B

// A-ring: 8 slots x one filtb row
#define SA_BYTES  (8*FILTB_ROW_B)   // 98304 B
#define SMEM_TOTAL (SA_BYTES + SB_BYTES)   // 153600 B

// ---------------------------------------------------------------------------
// fp32 -> fp8 e4m3 (OCP), RNE, input assumed in [0, 448).
// ---------------------------------------------------------------------------
__device__ __forceinline__ uint_t f32_to_e4m3(float f) {
  if (f < 0.015625f)                         // subnormal: m * 2^-9
    return (uint_t)__float2int_rn(f * 512.0f);
  uint_t b = __builtin_bit_cast(uint_t, f);
  int e = (int)(b >> 23) - 127;
  uint_t m = b & 0x7FFFFFu;
  uint_t keep = m >> 20;
  uint_t rest = m & 0xFFFFFu;
  keep += (rest > 0x80000u) || (rest == 0x80000u && (keep & 1u));
  if (keep == 8u) { keep = 0u; e += 1; }
  if (e > 8) return 0x7Eu;                   // saturate 448
  return (uint_t)(((e + 7) << 3) | keep);
}

// ---------------------------------------------------------------------------
// Prep (fused): zero filtb+prevb (blocks 0..), zero x2, then pack filters
// to fT2 [chp][45][12] (rows 16B-aligned, b-contiguous). Disjoint regions.
// ---------------------------------------------------------------------------
__global__ void prep_kernel(const float* __restrict__ ft, const float* __restrict__ fn,
                            float* __restrict__ fT2, uchar_t* __restrict__ wsz,
                            float* __restrict__ x2)
{
  const long e = (long)blockIdx.x * 256 + threadIdx.x;
  if (e < (long)ZERO16) {
    ((uint4_t*)wsz)[e] = uint4_t{0u, 0u, 0u, 0u};
  } else if (e < (long)(ZERO16 + X2Z16)) {
    ((uint4_t*)x2)[e - ZERO16] = uint4_t{0u, 0u, 0u, 0u};
  } else if (e < (long)PREP_WORK) {
    const int e2 = (int)(e - ZERO16 - X2Z16);
    const int chp = e2 / 540;
    const int rem = e2 - chp * 540;
    const int row = rem / 12;
    const int j = rem - row * 12;
    float v = 0.f;
    if (j < 11) {
      if (row < 33)      v = ft[chp * 363 + row * 11 + j];        // row = t*11+a
      else if (row < 44) v = fn[chp * 121 + (row - 33) * 11 + j]; // row-33 = a
    }
    fT2[e2] = v;
  }
}

// ---------------------------------------------------------------------------
// Stage 1: thread = (ch-pair chp) x (16-px row). Block 128 = 8 rows x 16 chp.
// mode 0: x -> x1 (fp32, LDS-transposed coalesced stores) AND direct fp8
//         byte-pack into filtb (replaces the old pack_kernel).
// mode 1: xprev -> prevb (fp8 e4m3).
// ---------------------------------------------------------------------------
__global__ __launch_bounds__(128, 4) void feat_kernel(
    const float* __restrict__ xcur, const float* __restrict__ xprev,
    const float* __restrict__ fT2,
    float* __restrict__ out_x1, uchar_t* __restrict__ prevb,
    uchar_t* __restrict__ filtb)
{
  __shared__ float sPx[3 * 18 * 28];
  __shared__ float sOut[32][9][20];    // [ch][r pad 9][px pad 20] bank-safe
  const int tid = threadIdx.x;
  const int chp = tid & 15;
  const int r = tid >> 4;              // 0..7
  const int j0 = blockIdx.x * 16;
  const int i0 = blockIdx.y * 8;
  const int i = i0 + r;
  const int mode = blockIdx.z;
  const float* __restrict__ xin = mode ? xprev : xcur;

  for (int e = tid; e < 3 * 18 * 26; e += 128) {
    const int t = e / 468;
    const int rem = e - t * 468;
    const int ri = rem / 26;
    const int ci = rem - ri * 26;
    sPx[(t * 18 + ri) * 28 + ci] = xin[((size_t)t * 394 + i0 + ri) * 394 + j0 + ci];
  }
  __syncthreads();

  const float* __restrict__ fbase = fT2 + chp * 540;

  float accT[16], accN[16];
#pragma unroll
  for (int p = 0; p < 16; ++p) { accT[p] = 0.f; accN[p] = 0.f; }

#pragma unroll
  for (int t = 0; t < 3; ++t) {
    for (int a = 0; a < 11; ++a) {
      const float* row = &sPx[(t * 18 + r + a) * 28];
      float wv[26];
#pragma unroll
      for (int k = 0; k < 6; ++k) {
        const f32x4 q = *(const f32x4*)(row + 4 * k);
        wv[4 * k + 0] = q[0]; wv[4 * k + 1] = q[1];
        wv[4 * k + 2] = q[2]; wv[4 * k + 3] = q[3];
      }
      wv[24] = row[24]; wv[25] = row[25];

      const float* fr = fbase + (t * 11 + a) * 12;
      const f32x4 fq0 = *(const f32x4*)(fr);
      const f32x4 fq1 = *(const f32x4*)(fr + 4);
      const f32x4 fq2 = *(const f32x4*)(fr + 8);
      float fv[12];
#pragma unroll
      for (int k = 0; k < 4; ++k) { fv[k] = fq0[k]; fv[4+k] = fq1[k]; fv[8+k] = fq2[k]; }
      float fv2[12];
      if (t == 2) {
        const float* fr2 = fbase + (33 + a) * 12;
        const f32x4 g0 = *(const f32x4*)(fr2);
        const f32x4 g1 = *(const f32x4*)(fr2 + 4);
        const f32x4 g2 = *(const f32x4*)(fr2 + 8);
#pragma unroll
        for (int k = 0; k < 4; ++k) { fv2[k] = g0[k]; fv2[4+k] = g1[k]; fv2[8+k] = g2[k]; }
      }

#pragma unroll
      for (int b = 0; b < 11; ++b) {
        const float fT = fv[b];
#pragma unroll
        for (int p = 0; p < 16; ++p) accT[p] = fmaf(wv[b + p], fT, accT[p]);
        if (t == 2) {
          const float fN = fv2[b];
#pragma unroll
          for (int p = 0; p < 16; ++p) accN[p] = fmaf(wv[b + p], fN, accN[p]);
        }
      }
    }
  }

  float o0[16], o1[16];
#pragma unroll
  for (int p = 0; p < 16; ++p) {
    const float vT = fmaxf(accT[p], 0.f) * 0.5f;   // temp: relu(conv)/2
    const float vN = fmaxf(accN[p], 0.f);
    float s = vT + vN;
    s += __shfl_xor(s, 1);  s += __shfl_xor(s, 2);
    s += __shfl_xor(s, 4);  s += __shfl_xor(s, 8);
    const float inv = 1.f / (s + EPSF);
    o0[p] = vT * inv;
    o1[p] = vN * inv;
  }

  if (mode == 0) {
    // Direct fp8 pack into filtb (replaces pack_kernel). Valid crop:
    // rows i 11..372 -> filtb row i-6 (5..366); cols c 11..372 ->
    // xb=(c-11)>>3, byte jj=(c-11)&7. Byte off replicates old pack:
    // (xb>>3)*2048 + ((xb>>1)&1)*1024 + ((xb>>2)&1)*512 + o*16
    // + (xb&1)*8 + jj. Out-of-crop slots stay memset-zero.
    if (i >= 11 && i <= 372) {
      uchar_t* const rowbase = filtb + (size_t)(i - 6) * FILTB_ROW_B;
#pragma unroll
      for (int p = 0; p < 16; ++p) {
        const int c = j0 + p;
        if (c >= 11 && c <= 372) {
          const int cb = c - 11;
          const int xb = cb >> 3;
          const int off = (xb >> 3) * 2048 + ((xb >> 1) & 1) * 1024 +
                          ((xb >> 2) & 1) * 512 + (xb & 1) * 8 + (cb & 7);
          rowbase[off + chp * 16]        = (uchar_t)f32_to_e4m3(o0[p]);
          rowbase[off + (chp + 16) * 16] = (uchar_t)f32_to_e4m3(o1[p]);
        }
      }
    }
    // Stage to LDS, then write x1 as 64B-contiguous segments.
#pragma unroll
    for (int p = 0; p < 16; ++p) {
      sOut[chp][r][p] = o0[p];
      sOut[chp + 16][r][p] = o1[p];
    }
    __syncthreads();
#pragma unroll
    for (int it = 0; it < 8; ++it) {
      const int idx = it * 128 + tid;        // 0..1023 = 32ch x 8r x 4seg
      const int seg = idx & 3;
      const int rr = (idx >> 2) & 7;
      const int chn = idx >> 5;
      const f32x4 v = {sOut[chn][rr][4 * seg], sOut[chn][rr][4 * seg + 1],
                       sOut[chn][rr][4 * seg + 2], sOut[chn][rr][4 * seg + 3]};
      *(f32x4*)(out_x1 + (size_t)chn * 147456 + (i0 + rr) * 384 + j0 + 4 * seg) = v;
    }
  } else {
    uint4_t u0, u1;
#pragma unroll
    for (int q = 0; q < 4; ++q) {
      u0[q] = f32_to_e4m3(o0[4*q]) | (f32_to_e4m3(o0[4*q+1]) << 8) |
              (f32_to_e4m3(o0[4*q+2]) << 16) | (f32_to_e4m3(o0[4*q+3]) << 24);
      u1[q] = f32_to_e4m3(o1[4*q]) | (f32_to_e4m3(o1[4*q+1]) << 8) |
              (f32_to_e4m3(o1[4*q+2]) << 16) | (f32_to_e4m3(o1[4*q+3]) << 24);
    }
    *(uint4_t*)(prevb + ((size_t)chp * 385 + i) * PREVB_STRIDE + j0) = u0;
    *(uint4_t*)(prevb + ((size_t)(chp + 16) * 385 + i) * PREVB_STRIDE + j0) = u1;
  }
}

// ---------------------------------------------------------------------------
// Stage 2: correlation via MX-scaled 32x32x64 fp8 MFMA (unit scales).
//   out[o,c,dy,dx] = sum_{y,x} filt[o][y-dy_a][x] * prev[c][y+6*dy_b][x+dx]
//   M=192=(dy_a 6)x(o 32); N=96: n = dyb*24+dx (dx 0..22, 23=pad);
//   K=(y, x): 6 kt64 steps of 64 per y.
// Block 1024 thr = 16 waves, producer-consumer (R20/R23 structure,
// UNCHANGED this round — corr is at its LDS-pipe plateau):
//   wv 0-11 = compute: 2 channel groups x 6 dy_a waves (pure-LDS K-loop,
//     0-deep loads, unroll 1); s_setprio(1) around the K-loop.
//   wv 12-15 = producers, one per SIMD: ALL staging.
// A: 8-slot LDS ring shared by both groups; producers write slot (y+6)&7.
// B: per-group double-buffered shifted-copy image. One barrier per y.
// Operand map (32x32x64 f8f6f4): m/n = lane&31, k = (lane>>5)*32 + j.
// C/D map: col = lane&31, row = (reg&3)+8*(reg>>2)+4*(lane>>5).
// ---------------------------------------------------------------------------
__global__ __launch_bounds__(1024, 4) void corr_kernel(
    const uchar_t* __restrict__ filtb, const uchar_t* __restrict__ prevb,
    float* __restrict__ x2)
{
  extern __shared__ uchar_t smem[];          // [A ring 98304][B 55296]

  const int tid = threadIdx.x;
  const int lane = tid & 63;
  const int wv = tid >> 6;               // 0..15
  const bool is_comp = (wv < 12);
  const int pw = wv - 12;                // producers 0..3 (neg for compute)
  const int cgu = is_comp ? ((wv >= 6) ? 1 : 0) : (pw >> 1);  // channel group
  const int w = is_comp ? (wv - 6 * ((wv >= 6) ? 1 : 0)) : 0; // dy_a
  const int kg = lane >> 5;              // k-group 0..1
  const int nn = lane & 31;              // n (or o) within tile

  const int chpair = blockIdx.x / NCHUNKS;     // 0..15
  const int chunk = blockIdx.x % NCHUNKS;      // 0..15; %8 == XCD
  const int ch = 2 * chpair + cgu;             // 0..31
  const int y0 = (chunk * YMAX) / NCHUNKS;     // balanced 22-23 y-steps
  const int y1 = ((chunk + 1) * YMAX) / NCHUNKS;

  uint_t* const sBg = (uint_t*)(smem + SA_BYTES) + cgu * (2 * (SB_ROW_B / 4));

  // Per-lane B window byte offsets within a y-row image (32B contiguous,
  // 8B-aligned): copy s = dx&7 is the row shifted by s bytes.
  int boffB[3];
#pragma unroll
  for (int nt = 0; nt < 3; ++nt) {
    const int n = nt * 32 + nn;          // 0..95
    const int dyb = n / 24;
    const int dxr = n - 24 * dyb;
    const int dx = (dxr < 23) ? dxr : 22;      // pad lane reads valid data
    const int s = dx & 7;
    boffB[nt] = dyb * SB_DYB_B + s * SB_COPY_B + (dx >> 3) * 8 + kg * 32;
  }

  // Producer B staging: 104 tasks per group from 2 waves (128 threads).
  const int tl = is_comp ? 0 : ((pw & 1) * 64 + lane);   // 0..127
  const bool b_act = (!is_comp) && (tl < 104);
  const int sdyb = b_act ? (tl / 26) : 0;
  const int sg = tl - 26 * (b_act ? (tl / 26) : 0);
  const uchar_t* srcbase = prevb + ((size_t)(ch * 385 + 6 * sdyb)) * PREVB_STRIDE;
  const int dstoff = sdyb * (SB_DYB_B / 4) + 4 * sg;     // word offset in buf

  // B: load row yy (24B window), expand to 8 byte-shifted copies in buf.
  auto stage_B = [&](int yy, int buf) {
    const uint_t* sw = (const uint_t*)(srcbase + (size_t)yy * PREVB_STRIDE) + 4 * sg;
    const uint4_t lo = *(const uint4_t*)(sw);
    const uint2_t hi = *(const uint2_t*)(sw + 4);
    const uint_t wd[6] = {lo.x, lo.y, lo.z, lo.w, hi.x, hi.y};
    uint_t* dst = sBg + buf * (SB_ROW_B / 4) + dstoff;
#pragma unroll
    for (int s = 0; s < 8; ++s) {
      const int off = s >> 2;
      const int b = (s & 3) * 8;
      uint4_t v;
      if (b == 0) {
        v = uint4_t{wd[off], wd[off + 1], wd[off + 2], wd[off + 3]};
      } else {
        v = uint4_t{(wd[off]     >> b) | (wd[off + 1] << (32 - b)),
                    (wd[off + 1] >> b) | (wd[off + 2] << (32 - b)),
                    (wd[off + 2] >> b) | (wd[off + 3] << (32 - b)),
                    (wd[off + 3] >> b) | (wd[off + 4] << (32 - b))};
      }
      *(uint4_t*)(dst + s * (SB_COPY_B / 4)) = v;
    }
  };

  // A: producers (ptid 0..255) copy one filtb row (48B each) into a slot.
  const int ptid = is_comp ? 0 : (pw * 64 + lane);
  auto stage_A = [&](int row, int slot) {
    const uchar_t* src = filtb + (size_t)row * FILTB_ROW_B + ptid * 48;
    uchar_t* dst = smem + (size_t)slot * FILTB_ROW_B + ptid * 48;
    const uint4_t v0 = *(const uint4_t*)(src);
    const uint4_t v1 = *(const uint4_t*)(src + 16);
    const uint4_t v2 = *(const uint4_t*)(src + 32);
    *(uint4_t*)(dst) = v0;
    *(uint4_t*)(dst + 16) = v1;
    *(uint4_t*)(dst + 32) = v2;
  };

  f32x16 acc[3];
#pragma unroll
  for (int nt = 0; nt < 3; ++nt)
#pragma unroll
    for (int r = 0; r < 16; ++r) acc[nt][r] = 0.f;

  // ---- Prologue (producers only) ----
  if (!is_comp) {
#pragma unroll
    for (int r6 = 0; r6 < 6; ++r6)
      stage_A(y0 + r6, (y0 + r6) & 7);
    if (b_act) stage_B(y0, 0);
  }
  __syncthreads();                       // A rows y0..y0+5 + B buf0 staged

  for (int y = y0; y < y1; ++y) {
    const int pb = (y - y0) & 1;         // B buffer consumers read this iter

    if (is_comp) {
      const char* sBrd = (const char*)sBg + pb * SB_ROW_B;
      const char* aRow = (const char*)smem +
          ((y + 5 - w) & 7) * FILTB_ROW_B + kg * 512 + nn * 16;

      // K-loop: 6 kt64 steps, pure LDS, minimal live registers.
      __builtin_amdgcn_s_setprio(1);
#pragma unroll 1
      for (int kt = 0; kt < 6; ++kt) {
        const char* ap = aRow + (kt << 11);
        const uint4_t a0 = *(const uint4_t*)(ap);          // h=0
        const uint4_t a1 = *(const uint4_t*)(ap + 1024);   // h=1
        const int8v Af = {(int)a0.x, (int)a0.y, (int)a0.z, (int)a0.w,
                          (int)a1.x, (int)a1.y, (int)a1.z, (int)a1.w};
#pragma unroll
        for (int nt = 0; nt < 3; ++nt) {
          const char* bp = sBrd + boffB[nt] + (kt << 6);
          const uint2_t b0 = *(const uint2_t*)(bp);
          const uint2_t b1 = *(const uint2_t*)(bp + 8);
          const uint2_t b2 = *(const uint2_t*)(bp + 16);
          const uint2_t b3 = *(const uint2_t*)(bp + 24);
          const int8v Bf = {(int)b0.x, (int)b0.y, (int)b1.x, (int)b1.y,
                            (int)b2.x, (int)b2.y, (int)b3.x, (int)b3.y};
          acc[nt] = __builtin_amdgcn_mfma_scale_f32_32x32x64_f8f6f4(
              Af, Bf, acc[nt], 0, 0,                // fmtA=FP8, fmtB=FP8
              0, 0x7F7F7F7F, 0, 0x7F7F7F7F);        // unit E8M0 scales
        }
      }
      __builtin_amdgcn_s_setprio(0);
    } else {
      // Producers: stage B row y+1 into buf pb^1 (consumers read pb), and
      // A row y+6 into ring slot (y+6)&7 (consumers read slots y..y+5).
      if (b_act && y + 1 < y1) stage_B(y + 1, pb ^ 1);
      if (y + 6 <= y1 + 4) stage_A(y + 6, (y + 6) & 7);
    }

    __syncthreads();                     // A row y+6 + B buf y+1 visible
  }

  // Epilogue: scale partials, atomically accumulate into x2[o][c][dy][dx].
  if (is_comp) {
#pragma unroll
    for (int nt = 0; nt < 3; ++nt) {
      const int n = nt * 32 + nn;
      const int dyb = n / 24;
      const int dxr = n - 24 * dyb;
      if (dxr < 23) {
        const int dy = w + 6 * dyb;
        if (dy <= 22) {
#pragma unroll
          for (int r = 0; r < 16; ++r) {
            const int o = (r & 3) + 8 * (r >> 2) + 4 * kg;   // C/D row
            atomicAdd(&x2[((o * 32 + ch) * 23 + dy) * 23 + dxr],
                      acc[nt][r] * INV_AREA);
          }
        }
      }
    }
  }
}

// ---------------------------------------------------------------------------
extern "C" void kernel_launch(void* const* d_in, const int* in_sizes, int n_in,
                              void* d_out, int out_size, void* d_ws, size_t ws_size,
                              hipStream_t stream)
{
  const float* x     = (const float*)d_in[0];   // [3][394][394]
  const float* xprev = (const float*)d_in[1];
  const float* ft    = (const float*)d_in[2];   // [16][3][11][11]
  const float* fn    = (const float*)d_in[3];   // [16][1][11][11]
  float* out = (float*)d_out;

  uchar_t* filtb = (uchar_t*)d_ws;
  uchar_t* prevb = filtb + FILTB_BYTES;
  float* fT2 = (float*)(prevb + PREVB_BYTES);

  static bool attr_set = false;
  if (!attr_set) {
    (void)hipFuncSetAttribute((const void*)corr_kernel,
        hipFuncAttributeMaxDynamicSharedMemorySize, SMEM_TOTAL);
    attr_set = true;
  }

  // 3 dispatches: prep (fused zeros + filter pack) -> feat (feats + x1 +
  // direct filtb/prevb pack) -> corr.
  prep_kernel<<<dim3((PREP_WORK + 255) / 256), 256, 0, stream>>>(
      ft, fn, fT2, (uchar_t*)d_ws, out + X1_N);
  feat_kernel<<<dim3(24, 48, 2), 128, 0, stream>>>(
      x, xprev, fT2, out, prevb, filtb);
  corr_kernel<<<dim3(16 * NCHUNKS), 1024, SMEM_TOTAL, stream>>>(
      filtb, prevb, out + X1_N);
}

// Round 15
// 259.885 us; speedup vs baseline: 1.2852x; 1.0045x over previous
//
#include <hip/hip_runtime.h>
#include <hip/hip_bf16.h>

// Net_22625887715641: fused conv-feats + channel-normalize + 32x32 normalized
// cross-correlation (23x23 shifts, 362x362 templates).
//
// R25 vs R24 (total 261.1, corr 125.0 unchanged — fusion win confirmed):
//  New ledger: feat ~= 125us (261 - corr 125 - prep ~4 - gaps ~6), running
//  at ~25% of its ~30us VALU/LDS floor. Cause: occupancy LDS-capped —
//  sPx 6KB + sOut 23KB = 28.7KB/block -> 5 blocks/CU = 2.5 waves/SIMD,
//  too few to hide the ~100 serialized per-(t,a) filter loads. R18 had
//  measured the sOut transpose-store path NEUTRAL vs direct stores, so
//  its 23KB buys nothing.
//  - feat: sOut DELETED; direct f32x4 x1 stores restored (pre-R18 path).
//    LDS 6KB/block -> launch_bounds(128,4)'s full 8 blocks/CU = 4 waves/
//    SIMD (1.6x occupancy); VGPR already capped <=128 by the bound.
//  - corr / prep byte-identical to R24 (corr at its LDS-pipe plateau:
//    R17/R18/R20/R23 all 124-128us; dedup line dead on register gate).

typedef unsigned short ushort_t;
typedef unsigned int uint_t;
typedef unsigned char uchar_t;
typedef __attribute__((ext_vector_type(4))) float f32x4;
typedef __attribute__((ext_vector_type(16))) float f32x16;
typedef __attribute__((ext_vector_type(4))) uint_t uint4_t;
typedef __attribute__((ext_vector_type(2))) uint_t uint2_t;
typedef __attribute__((ext_vector_type(8))) int int8v;

#define EPSF 2.2204460492503131e-16f
#define X1_N (32*384*384)
#define X2_N (32*32*23*23)

// filtb: fp8 [372 rows][kt64 6][h 2][kg 2][o 32][16B]; row = yf+5
#define FILTB_ROW_B 12288
#define FILTB_BYTES (372*48*32*8)
// prevb: fp8 [32 c][385 rows][432 x]; data rows 0..383 cols 0..383; zeros else
#define PREVB_STRIDE 432
#define PREVB_BYTES (32*385*PREVB_STRIDE)
#define ZERO_BYTES ((size_t)FILTB_BYTES + PREVB_BYTES)
// fT2: fp32 [16 chp][45 rows][12] after prevb
#define FT2_ELEMS (16*45*12)

// prep fused-zero ranges (16B units)
#define ZERO16 (ZERO_BYTES / 16)            // 618,336
#define X2Z16  ((X2_N * 4) / 16)            // 135,424
#define PREP_WORK (ZERO16 + X2Z16 + FT2_ELEMS)

#define YMAX 367            // y-steps 0..366
#define NCHUNKS 16          // 16 chpairs x 16 chunks = 256 blocks = 1/CU
#define INV_AREA (1.0f/131044.0f)

// One prev y-row image in LDS: [dyb 4][copy 8][432]; copy stride 432
#define SB_COPY_B 432
#define SB_DYB_B  (8*SB_COPY_B)     // 3456
#define SB_ROW_B  (4*SB_DYB_B)      // 13824 B per y-row image
#define SB_BYTES  (2*2*SB_ROW_B)    // [group][buf] = 55296 B

// A-ring: 8 slots x one filtb row
#define SA_BYTES  (8*FILTB_ROW_B)   // 98304 B
#define SMEM_TOTAL (SA_BYTES + SB_BYTES)   // 153600 B

// ---------------------------------------------------------------------------
// fp32 -> fp8 e4m3 (OCP), RNE, input assumed in [0, 448).
// ---------------------------------------------------------------------------
__device__ __forceinline__ uint_t f32_to_e4m3(float f) {
  if (f < 0.015625f)                         // subnormal: m * 2^-9
    return (uint_t)__float2int_rn(f * 512.0f);
  uint_t b = __builtin_bit_cast(uint_t, f);
  int e = (int)(b >> 23) - 127;
  uint_t m = b & 0x7FFFFFu;
  uint_t keep = m >> 20;
  uint_t rest = m & 0xFFFFFu;
  keep += (rest > 0x80000u) || (rest == 0x80000u && (keep & 1u));
  if (keep == 8u) { keep = 0u; e += 1; }
  if (e > 8) return 0x7Eu;                   // saturate 448
  return (uint_t)(((e + 7) << 3) | keep);
}

// ---------------------------------------------------------------------------
// Prep (fused): zero filtb+prevb, zero x2, pack filters to fT2.
// ---------------------------------------------------------------------------
__global__ void prep_kernel(const float* __restrict__ ft, const float* __restrict__ fn,
                            float* __restrict__ fT2, uchar_t* __restrict__ wsz,
                            float* __restrict__ x2)
{
  const long e = (long)blockIdx.x * 256 + threadIdx.x;
  if (e < (long)ZERO16) {
    ((uint4_t*)wsz)[e] = uint4_t{0u, 0u, 0u, 0u};
  } else if (e < (long)(ZERO16 + X2Z16)) {
    ((uint4_t*)x2)[e - ZERO16] = uint4_t{0u, 0u, 0u, 0u};
  } else if (e < (long)PREP_WORK) {
    const int e2 = (int)(e - ZERO16 - X2Z16);
    const int chp = e2 / 540;
    const int rem = e2 - chp * 540;
    const int row = rem / 12;
    const int j = rem - row * 12;
    float v = 0.f;
    if (j < 11) {
      if (row < 33)      v = ft[chp * 363 + row * 11 + j];        // row = t*11+a
      else if (row < 44) v = fn[chp * 121 + (row - 33) * 11 + j]; // row-33 = a
    }
    fT2[e2] = v;
  }
}

// ---------------------------------------------------------------------------
// Stage 1: thread = (ch-pair chp) x (16-px row). Block 128 = 8 rows x 16 chp.
// mode 0: x -> x1 (fp32 direct stores) AND direct fp8 byte-pack into filtb.
// mode 1: xprev -> prevb (fp8 e4m3).
// LDS = sPx only (6KB) -> 8 blocks/CU under launch_bounds(128,4).
// ---------------------------------------------------------------------------
__global__ __launch_bounds__(128, 4) void feat_kernel(
    const float* __restrict__ xcur, const float* __restrict__ xprev,
    const float* __restrict__ fT2,
    float* __restrict__ out_x1, uchar_t* __restrict__ prevb,
    uchar_t* __restrict__ filtb)
{
  __shared__ float sPx[3 * 18 * 28];
  const int tid = threadIdx.x;
  const int chp = tid & 15;
  const int r = tid >> 4;              // 0..7
  const int j0 = blockIdx.x * 16;
  const int i0 = blockIdx.y * 8;
  const int i = i0 + r;
  const int mode = blockIdx.z;
  const float* __restrict__ xin = mode ? xprev : xcur;

  for (int e = tid; e < 3 * 18 * 26; e += 128) {
    const int t = e / 468;
    const int rem = e - t * 468;
    const int ri = rem / 26;
    const int ci = rem - ri * 26;
    sPx[(t * 18 + ri) * 28 + ci] = xin[((size_t)t * 394 + i0 + ri) * 394 + j0 + ci];
  }
  __syncthreads();

  const float* __restrict__ fbase = fT2 + chp * 540;

  float accT[16], accN[16];
#pragma unroll
  for (int p = 0; p < 16; ++p) { accT[p] = 0.f; accN[p] = 0.f; }

#pragma unroll
  for (int t = 0; t < 3; ++t) {
    for (int a = 0; a < 11; ++a) {
      const float* row = &sPx[(t * 18 + r + a) * 28];
      float wv[26];
#pragma unroll
      for (int k = 0; k < 6; ++k) {
        const f32x4 q = *(const f32x4*)(row + 4 * k);
        wv[4 * k + 0] = q[0]; wv[4 * k + 1] = q[1];
        wv[4 * k + 2] = q[2]; wv[4 * k + 3] = q[3];
      }
      wv[24] = row[24]; wv[25] = row[25];

      const float* fr = fbase + (t * 11 + a) * 12;
      const f32x4 fq0 = *(const f32x4*)(fr);
      const f32x4 fq1 = *(const f32x4*)(fr + 4);
      const f32x4 fq2 = *(const f32x4*)(fr + 8);
      float fv[12];
#pragma unroll
      for (int k = 0; k < 4; ++k) { fv[k] = fq0[k]; fv[4+k] = fq1[k]; fv[8+k] = fq2[k]; }
      float fv2[12];
      if (t == 2) {
        const float* fr2 = fbase + (33 + a) * 12;
        const f32x4 g0 = *(const f32x4*)(fr2);
        const f32x4 g1 = *(const f32x4*)(fr2 + 4);
        const f32x4 g2 = *(const f32x4*)(fr2 + 8);
#pragma unroll
        for (int k = 0; k < 4; ++k) { fv2[k] = g0[k]; fv2[4+k] = g1[k]; fv2[8+k] = g2[k]; }
      }

#pragma unroll
      for (int b = 0; b < 11; ++b) {
        const float fT = fv[b];
#pragma unroll
        for (int p = 0; p < 16; ++p) accT[p] = fmaf(wv[b + p], fT, accT[p]);
        if (t == 2) {
          const float fN = fv2[b];
#pragma unroll
          for (int p = 0; p < 16; ++p) accN[p] = fmaf(wv[b + p], fN, accN[p]);
        }
      }
    }
  }

  float o0[16], o1[16];
#pragma unroll
  for (int p = 0; p < 16; ++p) {
    const float vT = fmaxf(accT[p], 0.f) * 0.5f;   // temp: relu(conv)/2
    const float vN = fmaxf(accN[p], 0.f);
    float s = vT + vN;
    s += __shfl_xor(s, 1);  s += __shfl_xor(s, 2);
    s += __shfl_xor(s, 4);  s += __shfl_xor(s, 8);
    const float inv = 1.f / (s + EPSF);
    o0[p] = vT * inv;
    o1[p] = vN * inv;
  }

  if (mode == 0) {
    // Direct fp8 pack into filtb (replaces pack_kernel). Valid crop:
    // rows i 11..372 -> filtb row i-6 (5..366); cols c 11..372 ->
    // xb=(c-11)>>3, byte jj=(c-11)&7. Byte off replicates old pack:
    // (xb>>3)*2048 + ((xb>>1)&1)*1024 + ((xb>>2)&1)*512 + o*16
    // + (xb&1)*8 + jj. Out-of-crop slots stay prep-zeroed.
    if (i >= 11 && i <= 372) {
      uchar_t* const rowbase = filtb + (size_t)(i - 6) * FILTB_ROW_B;
#pragma unroll
      for (int p = 0; p < 16; ++p) {
        const int c = j0 + p;
        if (c >= 11 && c <= 372) {
          const int cb = c - 11;
          const int xb = cb >> 3;
          const int off = (xb >> 3) * 2048 + ((xb >> 1) & 1) * 1024 +
                          ((xb >> 2) & 1) * 512 + (xb & 1) * 8 + (cb & 7);
          rowbase[off + chp * 16]        = (uchar_t)f32_to_e4m3(o0[p]);
          rowbase[off + (chp + 16) * 16] = (uchar_t)f32_to_e4m3(o1[p]);
        }
      }
    }
    // Direct x1 stores (pre-R18 path; measured equivalent to the LDS
    // transpose, and dropping sOut frees 23KB LDS -> 8 blocks/CU).
#pragma unroll
    for (int q = 0; q < 4; ++q) {
      f32x4 v0 = {o0[4*q], o0[4*q+1], o0[4*q+2], o0[4*q+3]};
      f32x4 v1 = {o1[4*q], o1[4*q+1], o1[4*q+2], o1[4*q+3]};
      *(f32x4*)(out_x1 + (size_t)chp * 147456 + i * 384 + j0 + 4 * q) = v0;
      *(f32x4*)(out_x1 + (size_t)(chp + 16) * 147456 + i * 384 + j0 + 4 * q) = v1;
    }
  } else {
    uint4_t u0, u1;
#pragma unroll
    for (int q = 0; q < 4; ++q) {
      u0[q] = f32_to_e4m3(o0[4*q]) | (f32_to_e4m3(o0[4*q+1]) << 8) |
              (f32_to_e4m3(o0[4*q+2]) << 16) | (f32_to_e4m3(o0[4*q+3]) << 24);
      u1[q] = f32_to_e4m3(o1[4*q]) | (f32_to_e4m3(o1[4*q+1]) << 8) |
              (f32_to_e4m3(o1[4*q+2]) << 16) | (f32_to_e4m3(o1[4*q+3]) << 24);
    }
    *(uint4_t*)(prevb + ((size_t)chp * 385 + i) * PREVB_STRIDE + j0) = u0;
    *(uint4_t*)(prevb + ((size_t)(chp + 16) * 385 + i) * PREVB_STRIDE + j0) = u1;
  }
}

// ---------------------------------------------------------------------------
// Stage 2: correlation via MX-scaled 32x32x64 fp8 MFMA (unit scales).
//   out[o,c,dy,dx] = sum_{y,x} filt[o][y-dy_a][x] * prev[c][y+6*dy_b][x+dx]
//   M=192=(dy_a 6)x(o 32); N=96: n = dyb*24+dx (dx 0..22, 23=pad);
//   K=(y, x): 6 kt64 steps of 64 per y.
// Block 1024 thr = 16 waves, producer-consumer (R20/R23 structure,
// UNCHANGED — corr is at its LDS-pipe plateau):
//   wv 0-11 = compute: 2 channel groups x 6 dy_a waves (pure-LDS K-loop,
//     0-deep loads, unroll 1); s_setprio(1) around the K-loop.
//   wv 12-15 = producers, one per SIMD: ALL staging.
// A: 8-slot LDS ring shared by both groups; producers write slot (y+6)&7.
// B: per-group double-buffered shifted-copy image. One barrier per y.
// Operand map (32x32x64 f8f6f4): m/n = lane&31, k = (lane>>5)*32 + j.
// C/D map: col = lane&31, row = (reg&3)+8*(reg>>2)+4*(lane>>5).
// ---------------------------------------------------------------------------
__global__ __launch_bounds__(1024, 4) void corr_kernel(
    const uchar_t* __restrict__ filtb, const uchar_t* __restrict__ prevb,
    float* __restrict__ x2)
{
  extern __shared__ uchar_t smem[];          // [A ring 98304][B 55296]

  const int tid = threadIdx.x;
  const int lane = tid & 63;
  const int wv = tid >> 6;               // 0..15
  const bool is_comp = (wv < 12);
  const int pw = wv - 12;                // producers 0..3 (neg for compute)
  const int cgu = is_comp ? ((wv >= 6) ? 1 : 0) : (pw >> 1);  // channel group
  const int w = is_comp ? (wv - 6 * ((wv >= 6) ? 1 : 0)) : 0; // dy_a
  const int kg = lane >> 5;              // k-group 0..1
  const int nn = lane & 31;              // n (or o) within tile

  const int chpair = blockIdx.x / NCHUNKS;     // 0..15
  const int chunk = blockIdx.x % NCHUNKS;      // 0..15; %8 == XCD
  const int ch = 2 * chpair + cgu;             // 0..31
  const int y0 = (chunk * YMAX) / NCHUNKS;     // balanced 22-23 y-steps
  const int y1 = ((chunk + 1) * YMAX) / NCHUNKS;

  uint_t* const sBg = (uint_t*)(smem + SA_BYTES) + cgu * (2 * (SB_ROW_B / 4));

  // Per-lane B window byte offsets within a y-row image (32B contiguous,
  // 8B-aligned): copy s = dx&7 is the row shifted by s bytes.
  int boffB[3];
#pragma unroll
  for (int nt = 0; nt < 3; ++nt) {
    const int n = nt * 32 + nn;          // 0..95
    const int dyb = n / 24;
    const int dxr = n - 24 * dyb;
    const int dx = (dxr < 23) ? dxr : 22;      // pad lane reads valid data
    const int s = dx & 7;
    boffB[nt] = dyb * SB_DYB_B + s * SB_COPY_B + (dx >> 3) * 8 + kg * 32;
  }

  // Producer B staging: 104 tasks per group from 2 waves (128 threads).
  const int tl = is_comp ? 0 : ((pw & 1) * 64 + lane);   // 0..127
  const bool b_act = (!is_comp) && (tl < 104);
  const int sdyb = b_act ? (tl / 26) : 0;
  const int sg = tl - 26 * (b_act ? (tl / 26) : 0);
  const uchar_t* srcbase = prevb + ((size_t)(ch * 385 + 6 * sdyb)) * PREVB_STRIDE;
  const int dstoff = sdyb * (SB_DYB_B / 4) + 4 * sg;     // word offset in buf

  // B: load row yy (24B window), expand to 8 byte-shifted copies in buf.
  auto stage_B = [&](int yy, int buf) {
    const uint_t* sw = (const uint_t*)(srcbase + (size_t)yy * PREVB_STRIDE) + 4 * sg;
    const uint4_t lo = *(const uint4_t*)(sw);
    const uint2_t hi = *(const uint2_t*)(sw + 4);
    const uint_t wd[6] = {lo.x, lo.y, lo.z, lo.w, hi.x, hi.y};
    uint_t* dst = sBg + buf * (SB_ROW_B / 4) + dstoff;
#pragma unroll
    for (int s = 0; s < 8; ++s) {
      const int off = s >> 2;
      const int b = (s & 3) * 8;
      uint4_t v;
      if (b == 0) {
        v = uint4_t{wd[off], wd[off + 1], wd[off + 2], wd[off + 3]};
      } else {
        v = uint4_t{(wd[off]     >> b) | (wd[off + 1] << (32 - b)),
                    (wd[off + 1] >> b) | (wd[off + 2] << (32 - b)),
                    (wd[off + 2] >> b) | (wd[off + 3] << (32 - b)),
                    (wd[off + 3] >> b) | (wd[off + 4] << (32 - b))};
      }
      *(uint4_t*)(dst + s * (SB_COPY_B / 4)) = v;
    }
  };

  // A: producers (ptid 0..255) copy one filtb row (48B each) into a slot.
  const int ptid = is_comp ? 0 : (pw * 64 + lane);
  auto stage_A = [&](int row, int slot) {
    const uchar_t* src = filtb + (size_t)row * FILTB_ROW_B + ptid * 48;
    uchar_t* dst = smem + (size_t)slot * FILTB_ROW_B + ptid * 48;
    const uint4_t v0 = *(const uint4_t*)(src);
    const uint4_t v1 = *(const uint4_t*)(src + 16);
    const uint4_t v2 = *(const uint4_t*)(src + 32);
    *(uint4_t*)(dst) = v0;
    *(uint4_t*)(dst + 16) = v1;
    *(uint4_t*)(dst + 32) = v2;
  };

  f32x16 acc[3];
#pragma unroll
  for (int nt = 0; nt < 3; ++nt)
#pragma unroll
    for (int r = 0; r < 16; ++r) acc[nt][r] = 0.f;

  // ---- Prologue (producers only) ----
  if (!is_comp) {
#pragma unroll
    for (int r6 = 0; r6 < 6; ++r6)
      stage_A(y0 + r6, (y0 + r6) & 7);
    if (b_act) stage_B(y0, 0);
  }
  __syncthreads();                       // A rows y0..y0+5 + B buf0 staged

  for (int y = y0; y < y1; ++y) {
    const int pb = (y - y0) & 1;         // B buffer consumers read this iter

    if (is_comp) {
      const char* sBrd = (const char*)sBg + pb * SB_ROW_B;
      const char* aRow = (const char*)smem +
          ((y + 5 - w) & 7) * FILTB_ROW_B + kg * 512 + nn * 16;

      // K-loop: 6 kt64 steps, pure LDS, minimal live registers.
      __builtin_amdgcn_s_setprio(1);
#pragma unroll 1
      for (int kt = 0; kt < 6; ++kt) {
        const char* ap = aRow + (kt << 11);
        const uint4_t a0 = *(const uint4_t*)(ap);          // h=0
        const uint4_t a1 = *(const uint4_t*)(ap + 1024);   // h=1
        const int8v Af = {(int)a0.x, (int)a0.y, (int)a0.z, (int)a0.w,
                          (int)a1.x, (int)a1.y, (int)a1.z, (int)a1.w};
#pragma unroll
        for (int nt = 0; nt < 3; ++nt) {
          const char* bp = sBrd + boffB[nt] + (kt << 6);
          const uint2_t b0 = *(const uint2_t*)(bp);
          const uint2_t b1 = *(const uint2_t*)(bp + 8);
          const uint2_t b2 = *(const uint2_t*)(bp + 16);
          const uint2_t b3 = *(const uint2_t*)(bp + 24);
          const int8v Bf = {(int)b0.x, (int)b0.y, (int)b1.x, (int)b1.y,
                            (int)b2.x, (int)b2.y, (int)b3.x, (int)b3.y};
          acc[nt] = __builtin_amdgcn_mfma_scale_f32_32x32x64_f8f6f4(
              Af, Bf, acc[nt], 0, 0,                // fmtA=FP8, fmtB=FP8
              0, 0x7F7F7F7F, 0, 0x7F7F7F7F);        // unit E8M0 scales
        }
      }
      __builtin_amdgcn_s_setprio(0);
    } else {
      // Producers: stage B row y+1 into buf pb^1 (consumers read pb), and
      // A row y+6 into ring slot (y+6)&7 (consumers read slots y..y+5).
      if (b_act && y + 1 < y1) stage_B(y + 1, pb ^ 1);
      if (y + 6 <= y1 + 4) stage_A(y + 6, (y + 6) & 7);
    }

    __syncthreads();                     // A row y+6 + B buf y+1 visible
  }

  // Epilogue: scale partials, atomically accumulate into x2[o][c][dy][dx].
  if (is_comp) {
#pragma unroll
    for (int nt = 0; nt < 3; ++nt) {
      const int n = nt * 32 + nn;
      const int dyb = n / 24;
      const int dxr = n - 24 * dyb;
      if (dxr < 23) {
        const int dy = w + 6 * dyb;
        if (dy <= 22) {
#pragma unroll
          for (int r = 0; r < 16; ++r) {
            const int o = (r & 3) + 8 * (r >> 2) + 4 * kg;   // C/D row
            atomicAdd(&x2[((o * 32 + ch) * 23 + dy) * 23 + dxr],
                      acc[nt][r] * INV_AREA);
          }
        }
      }
    }
  }
}

// ---------------------------------------------------------------------------
extern "C" void kernel_launch(void* const* d_in, const int* in_sizes, int n_in,
                              void* d_out, int out_size, void* d_ws, size_t ws_size,
                              hipStream_t stream)
{
  const float* x     = (const float*)d_in[0];   // [3][394][394]
  const float* xprev = (const float*)d_in[1];
  const float* ft    = (const float*)d_in[2];   // [16][3][11][11]
  const float* fn    = (const float*)d_in[3];   // [16][1][11][11]
  float* out = (float*)d_out;

  uchar_t* filtb = (uchar_t*)d_ws;
  uchar_t* prevb = filtb + FILTB_BYTES;
  float* fT2 = (float*)(prevb + PREVB_BYTES);

  static bool attr_set = false;
  if (!attr_set) {
    (void)hipFuncSetAttribute((const void*)corr_kernel,
        hipFuncAttributeMaxDynamicSharedMemorySize, SMEM_TOTAL);
    attr_set = true;
  }

  // 3 dispatches: prep (fused zeros + filter pack) -> feat (feats + x1 +
  // direct filtb/prevb pack) -> corr.
  prep_kernel<<<dim3((PREP_WORK + 255) / 256), 256, 0, stream>>>(
      ft, fn, fT2, (uchar_t*)d_ws, out + X1_N);
  feat_kernel<<<dim3(24, 48, 2), 128, 0, stream>>>(
      x, xprev, fT2, out, prevb, filtb);
  corr_kernel<<<dim3(16 * NCHUNKS), 1024, SMEM_TOTAL, stream>>>(
      filtb, prevb, out + X1_N);
}